// Round 14
// baseline (164.282 us; speedup 1.0000x reference)
//
#include <hip/hip_runtime.h>
#include <stdint.h>

typedef _Float16 half8  __attribute__((ext_vector_type(8)));
typedef float    floatx4 __attribute__((ext_vector_type(4)));
typedef uint32_t uint4v  __attribute__((ext_vector_type(4)));

#define KDIM 4096
#define ODIM 11008
#define NG   32
#define OT   32          // o-cols per block
#define NBLK (ODIM / OT) // 344 blocks, each full K
#define LPITCH 36        // LDS dwords per o-row (32 data + 4 pad -> 2-way max)

__device__ __forceinline__ uint32_t pk_f16(float a, float b) {
    return __builtin_bit_cast(uint32_t, __builtin_amdgcn_cvt_pkrtz(a, b));
}

// x fp32 [64][4096] -> f16 fragments xh2[g][ks][mt][lane] (uint4, halves
// slot-paired (x_j, x_{j+4})) + per-(group,m) row sums xsumT[32][64].
// (layout HW-verified R10-R13, absmax 0.125)
__global__ __launch_bounds__(256) void cvt_x_kernel(
    const float4* __restrict__ x, uint4v* __restrict__ xh2,
    float* __restrict__ xsumT)
{
    const int i = blockIdx.x * 256 + threadIdx.x;
    const float4 f0 = x[2 * i];
    const float4 f1 = x[2 * i + 1];
    const uint4v v = {pk_f16(f0.x, f1.x), pk_f16(f0.y, f1.y),
                      pk_f16(f0.z, f1.z), pk_f16(f0.w, f1.w)};
    const int m  = i >> 9, c = i & 511;
    const int g  = c >> 4, cg = c & 15, q = cg >> 2, ks = cg & 3;
    const int mt = m >> 4, ml = m & 15;
    xh2[((size_t)(g * 4 + ks) * 4 + mt) * 64 + q * 16 + ml] = v;

    float p = f0.x + f0.y + f0.z + f0.w + f1.x + f1.y + f1.z + f1.w;
    p += __shfl_xor(p, 1);
    p += __shfl_xor(p, 2);
    p += __shfl_xor(p, 4);
    p += __shfl_xor(p, 8);
    if ((threadIdx.x & 15) == 0) xsumT[g * 64 + m] = p;
}

// Block: 32 o-cols x FULL K (grid = 344; no k-split, no partials, no atomics).
// 4 waves = 4 M-tiles, each covers 32 o (2 subtiles) x 1024 MACs-k per MFMA set.
// qweight deduped via double-buffered LDS in GROUP-PAIR units (4 KB / stage,
// all 256 threads, one barrier per pair) with register prefetch DISTANCE 2
// (2 x uint4 = 8 VGPR). x-frags register dbuf distance 1 (L2-resident xh2).
// Zero-point via rowsum correction. Direct final stores.
__global__ __launch_bounds__(256, 2) void w4a16_kernel(
    const uint4v*   __restrict__ xh2,    // [32][4][4][64] uint4
    const uint32_t* __restrict__ qw,     // [11008][512] dwords
    const uint32_t* __restrict__ qz,     // [11008][4]
    const float*    __restrict__ sc,     // [11008][32] (fp32-upcast fp16)
    const float*    __restrict__ xsumT,  // [32][64]
    float*          __restrict__ out)    // [64][11008]
{
    __shared__ uint32_t qlds[2][OT * LPITCH];   // 2 x 4608 dwords = 36 KB

    const int t    = threadIdx.x;
    const int wv   = t >> 6;            // wave -> M-tile
    const int lane = t & 63;
    const int q    = lane >> 4;
    const int ml   = lane & 15;
    const int o0   = blockIdx.x * OT;

    // staging role: thread t -> o-row r (0..31), 16-B chunk c (0..7) of a
    // 128-B group-pair slice
    const int r = t >> 3, c = t & 7;
    const uint32_t* sgp = qw + (size_t)(o0 + r) * 512 + c * 4;
    const int widx = r * LPITCH + c * 4;

    // register prefetch distance 2 (group-pairs 0 and 1)
    uint4v ureg[2];
    ureg[0] = *reinterpret_cast<const uint4v*>(sgp);
    ureg[1] = *reinterpret_cast<const uint4v*>(sgp + 32);

    // x fragments: wave-owned m-tile, fragment-ordered; dbuf distance 1
    const uint4v* xp = xh2 + (size_t)wv * 64 + lane;   // + (g*4+ks)*256
    uint4v ax[2][4];
    #pragma unroll
    for (int ks = 0; ks < 4; ++ks) ax[0][ks] = xp[ks * 256];

    // hoisted zero rows (uint4 = all 32 group nibbles) per subtile
    uint4v zr[2];
    #pragma unroll
    for (int sub = 0; sub < 2; ++sub)
        zr[sub] = *reinterpret_cast<const uint4v*>(
            qz + (size_t)(o0 + sub * 16 + ml) * 4);

    const int mrow = wv * 16 + q * 4;
    floatx4 acc[2] = {{0.f,0.f,0.f,0.f},{0.f,0.f,0.f,0.f}};

    #pragma unroll
    for (int gp = 0; gp < 16; ++gp) {
        // write this pair's staged data, sync, then top up the prefetch queue
        *reinterpret_cast<uint4v*>(&qlds[gp & 1][widx]) = ureg[gp & 1];
        __syncthreads();
        if (gp + 2 < 16)
            ureg[gp & 1] = *reinterpret_cast<const uint4v*>(sgp + (gp + 2) * 32);

        #pragma unroll
        for (int gi = 0; gi < 2; ++gi) {
            const int g = gp * 2 + gi;
            if (g + 1 < 32) {
                #pragma unroll
                for (int ks = 0; ks < 4; ++ks)
                    ax[(g + 1) & 1][ks] = xp[(size_t)((g + 1) * 4 + ks) * 256];
            }
            const floatx4 xsg = *reinterpret_cast<const floatx4*>(
                xsumT + g * 64 + mrow);

            #pragma unroll
            for (int sub = 0; sub < 2; ++sub) {
                const uint4v qf = *reinterpret_cast<const uint4v*>(
                    &qlds[gp & 1][(sub * 16 + ml) * LPITCH + gi * 16 + q * 4]);
                const float    s  = sc[(size_t)(o0 + sub * 16 + ml) * NG + g];
                const uint32_t zn = (zr[sub][g >> 3] >> ((g & 7) * 4)) & 0xFu;
                const float    czs = s * (1024.0f + (float)zn);

                floatx4 tmp = {0.f, 0.f, 0.f, 0.f};
                #pragma unroll
                for (int ks = 0; ks < 4; ++ks) {
                    const uint32_t ud = qf[ks];
                    const uint4v bw = {
                        ( ud         & 0x000F000Fu) | 0x64006400u,
                        ((ud >> 4)   & 0x000F000Fu) | 0x64006400u,
                        ((ud >> 8)   & 0x000F000Fu) | 0x64006400u,
                        ((ud >> 12)  & 0x000F000Fu) | 0x64006400u};
                    const half8 b = __builtin_bit_cast(half8, bw);
                    tmp = __builtin_amdgcn_mfma_f32_16x16x32_f16(
                        __builtin_bit_cast(half8, ax[g & 1][ks]), b, tmp, 0, 0, 0);
                }
                #pragma unroll
                for (int rr = 0; rr < 4; ++rr)
                    acc[sub][rr] += s * tmp[rr] - czs * xsg[rr];
            }
        }
    }

    // direct final stores (full K accumulated in-register)
    #pragma unroll
    for (int sub = 0; sub < 2; ++sub) {
        float* op = out + (size_t)mrow * ODIM + o0 + sub * 16 + ml;
        op[0]                = acc[sub][0];
        op[(size_t)ODIM]     = acc[sub][1];
        op[2 * (size_t)ODIM] = acc[sub][2];
        op[3 * (size_t)ODIM] = acc[sub][3];
    }
}

extern "C" void kernel_launch(void* const* d_in, const int* in_sizes, int n_in,
                              void* d_out, int out_size, void* d_ws, size_t ws_size,
                              hipStream_t stream) {
    const float*    x       = (const float*)d_in[0];
    const uint32_t* qweight = (const uint32_t*)d_in[1];
    const uint32_t* qzeros  = (const uint32_t*)d_in[2];
    const float*    scales  = (const float*)d_in[3];
    float* out = (float*)d_out;

    uint4v* xh2   = (uint4v*)d_ws;                         // 512 KB
    float*  xsumT = (float*)((char*)d_ws + 512 * 1024);    // 8 KB

    cvt_x_kernel<<<dim3(128), dim3(256), 0, stream>>>((const float4*)x, xh2, xsumT);
    w4a16_kernel<<<dim3(NBLK), dim3(256), 0, stream>>>(
        xh2, qweight, qzeros, scales, xsumT, out);
}

// Round 15
// 93.710 us; speedup vs baseline: 1.7531x; 1.7531x over previous
//
#include <hip/hip_runtime.h>
#include <stdint.h>

typedef _Float16 half8  __attribute__((ext_vector_type(8)));
typedef float    floatx4 __attribute__((ext_vector_type(4)));
typedef uint32_t uint4v  __attribute__((ext_vector_type(4)));

#define KDIM 4096
#define ODIM 11008
#define NG   32

__device__ __forceinline__ uint32_t pk_f16(float a, float b) {
    return __builtin_bit_cast(uint32_t, __builtin_amdgcn_cvt_pkrtz(a, b));
}

// x fp32 [64][4096] -> f16 fragments xh2[g][ks][mt][lane] (uint4, halves
// slot-paired (x_j, x_{j+4})) + per-(group,m) row sums xsumT[32][64].
// (layout HW-verified R10-R14, absmax 0.125)
__global__ __launch_bounds__(256) void cvt_x_kernel(
    const float4* __restrict__ x, uint4v* __restrict__ xh2,
    float* __restrict__ xsumT)
{
    const int i = blockIdx.x * 256 + threadIdx.x;
    const float4 f0 = x[2 * i];
    const float4 f1 = x[2 * i + 1];
    const uint4v v = {pk_f16(f0.x, f1.x), pk_f16(f0.y, f1.y),
                      pk_f16(f0.z, f1.z), pk_f16(f0.w, f1.w)};
    const int m  = i >> 9, c = i & 511;
    const int g  = c >> 4, cg = c & 15, q = cg >> 2, ks = cg & 3;
    const int mt = m >> 4, ml = m & 15;
    xh2[((size_t)(g * 4 + ks) * 4 + mt) * 64 + q * 16 + ml] = v;

    float p = f0.x + f0.y + f0.z + f0.w + f1.x + f1.y + f1.z + f1.w;
    p += __shfl_xor(p, 1);
    p += __shfl_xor(p, 2);
    p += __shfl_xor(p, 4);
    p += __shfl_xor(p, 8);
    if ((threadIdx.x & 15) == 0) xsumT[g * 64 + m] = p;
}

// Block: 16 o-cols x FULL K; 4 waves = 4 k-quarters, each covering all 64 m
// (4 M-tiles). qweight unique per wave: 1 uint4/lane/group, manual distance-2
// circular prefetch, NO main-loop barriers. g-loop ROLLED (#pragma unroll 1)
// to bound live ranges (anti-spill; lesson of R11/R13/R14). x-frag loads
// batched 8-at-a-time (two MLP bursts per group). Epilogue: verified 16-KB
// LDS k-reduce + direct stores. Grid: 688 blocks.
__global__ __launch_bounds__(256, 2) void w4a16_kernel(
    const uint4v*   __restrict__ xh2,    // [32][4][4][64] uint4
    const uint4v*   __restrict__ qw,     // [11008][128] uint4
    const uint32_t* __restrict__ qz,     // [11008][4]
    const float*    __restrict__ sc,     // [11008][32] (fp32-upcast fp16)
    const float*    __restrict__ xsumT,  // [32][64]
    float*          __restrict__ out)    // [64][11008]
{
    __shared__ float red[4][16][64];     // 16 KB

    const int t    = threadIdx.x;
    const int kw   = t >> 6;            // wave -> k-quarter (groups kw*8..+7)
    const int lane = t & 63;
    const int q    = lane >> 4;
    const int ml   = lane & 15;

    const int o0 = blockIdx.x * 16;
    const int o  = o0 + ml;             // B col = ml
    const int g0 = kw * 8;

    const uint4v* qwp = qw + (size_t)o * 128 + g0 * 4 + q;
    const uint32_t zdw = qz[(size_t)o * 4 + kw];      // 8 nibbles = 8 groups
    const floatx4 sv0 = *reinterpret_cast<const floatx4*>(sc + (size_t)o * NG + g0);
    const floatx4 sv1 = *reinterpret_cast<const floatx4*>(sc + (size_t)o * NG + g0 + 4);

    const uint4v* xp = xh2 + (size_t)g0 * 1024 + lane;   // + (gl*16 + i)*64
    const float*  xs = xsumT + (size_t)g0 * 64 + q * 4;  // + gl*64 + mt*16

    floatx4 acc[4] = {{0.f,0.f,0.f,0.f},{0.f,0.f,0.f,0.f},
                      {0.f,0.f,0.f,0.f},{0.f,0.f,0.f,0.f}};

    // distance-2 circular qweight prefetch (8 VGPR)
    uint4v ubuf[2];
    ubuf[0] = qwp[0];
    ubuf[1] = qwp[4];

    #pragma unroll 1
    for (int gl = 0; gl < 8; ++gl) {
        const uint4v ucur = ubuf[gl & 1];
        if (gl + 2 < 8) ubuf[gl & 1] = qwp[(gl + 2) * 4];

        const uint32_t zn  = (zdw >> (gl * 4)) & 0xFu;
        const float    s   = (gl < 4) ? sv0[gl] : sv1[gl - 4];
        const float    czs = s * (1024.0f + (float)zn);

        floatx4 tmp[4] = {{0.f,0.f,0.f,0.f},{0.f,0.f,0.f,0.f},
                          {0.f,0.f,0.f,0.f},{0.f,0.f,0.f,0.f}};

        #pragma unroll
        for (int h = 0; h < 2; ++h) {           // half-group: ks = 2h, 2h+1
            // batched 8-load MLP burst (32 VGPR live)
            uint4v ax[8];
            #pragma unroll
            for (int i = 0; i < 8; ++i)
                ax[i] = xp[(size_t)(gl * 16 + h * 8 + i) * 64];

            #pragma unroll
            for (int k2 = 0; k2 < 2; ++k2) {
                const int ks = h * 2 + k2;
                const uint32_t ud = ucur[ks];
                const uint4v bw = {
                    ( ud         & 0x000F000Fu) | 0x64006400u,
                    ((ud >> 4)   & 0x000F000Fu) | 0x64006400u,
                    ((ud >> 8)   & 0x000F000Fu) | 0x64006400u,
                    ((ud >> 12)  & 0x000F000Fu) | 0x64006400u};
                const half8 b = __builtin_bit_cast(half8, bw);
                #pragma unroll
                for (int mt = 0; mt < 4; ++mt)
                    tmp[mt] = __builtin_amdgcn_mfma_f32_16x16x32_f16(
                        __builtin_bit_cast(half8, ax[k2 * 4 + mt]), b, tmp[mt],
                        0, 0, 0);
            }
        }

        // scale + zero-point correction (xsumT is L1-resident, 8 KB)
        #pragma unroll
        for (int mt = 0; mt < 4; ++mt) {
            const floatx4 xg = *reinterpret_cast<const floatx4*>(
                xs + gl * 64 + mt * 16);
            #pragma unroll
            for (int r = 0; r < 4; ++r)
                acc[mt][r] += s * tmp[mt][r] - czs * xg[r];
        }
    }

    // cross-wave k-reduce through LDS, then direct final stores (R12-verified)
    #pragma unroll
    for (int mt = 0; mt < 4; ++mt)
        #pragma unroll
        for (int r = 0; r < 4; ++r)
            red[kw][mt * 4 + r][lane] = acc[mt][r];
    __syncthreads();

    const int mt2 = t >> 6;             // reuse wave id as output M-tile
    #pragma unroll
    for (int r = 0; r < 4; ++r) {
        const int i = mt2 * 4 + r;
        const float sum = red[0][i][lane] + red[1][i][lane]
                        + red[2][i][lane] + red[3][i][lane];
        out[(size_t)(mt2 * 16 + q * 4 + r) * ODIM + o] = sum;
    }
}

extern "C" void kernel_launch(void* const* d_in, const int* in_sizes, int n_in,
                              void* d_out, int out_size, void* d_ws, size_t ws_size,
                              hipStream_t stream) {
    const float*    x       = (const float*)d_in[0];
    const uint32_t* qweight = (const uint32_t*)d_in[1];
    const uint32_t* qzeros  = (const uint32_t*)d_in[2];
    const float*    scales  = (const float*)d_in[3];
    float* out = (float*)d_out;

    uint4v* xh2   = (uint4v*)d_ws;                         // 512 KB
    float*  xsumT = (float*)((char*)d_ws + 512 * 1024);    // 8 KB

    cvt_x_kernel<<<dim3(128), dim3(256), 0, stream>>>((const float4*)x, xh2, xsumT);
    w4a16_kernel<<<dim3(ODIM / 16), dim3(256), 0, stream>>>(
        xh2, (const uint4v*)qweight, qzeros, scales, xsumT, out);
}